// Round 1
// baseline (876.581 us; speedup 1.0000x reference)
//
#include <hip/hip_runtime.h>
#include <hip/hip_bf16.h>
#include <math.h>

#define B_   2
#define S_   2048
#define D_   1024
#define H_   16
#define HD_  64
#define WIN_ 256

// ---------------------------------------------------------------------------
// RoPE cos/sin table: [S][32] each. Angle computed with f32 rounding (matches
// jnp f32 outer product), trig evaluated in f64 for accuracy.
// ---------------------------------------------------------------------------
__global__ void rope_table_kernel(float* __restrict__ cosT, float* __restrict__ sinT)
{
    int idx = blockIdx.x * 256 + threadIdx.x;
    if (idx >= S_ * 32) return;
    int s = idx >> 5;
    int i = idx & 31;
    float invf = 1.0f / powf(10000.0f, (float)(2 * i) / 64.0f);
    float ang  = (float)s * invf;                 // f32 rounding like reference
    double a = (double)ang;
    cosT[idx] = (float)cos(a);
    sinT[idx] = (float)sin(a);
}

// ---------------------------------------------------------------------------
// Fused QKV projection: Y = X @ W^T + b for W in {Wq,Wk,Wv}.
// X: [4096,1024] f32.  Combined N = 3072.  Tiles 128x128, BK=16, 256 thr,
// 8x8 outputs/thread (2x2 quads of 4x4). Epilogue scatters to [B,H,S,64].
// ---------------------------------------------------------------------------
__global__ __launch_bounds__(256)
void qkv_gemm_kernel(const float* __restrict__ X,
                     const float* __restrict__ Wq, const float* __restrict__ Wk,
                     const float* __restrict__ Wv,
                     const float* __restrict__ bq, const float* __restrict__ bk,
                     const float* __restrict__ bv,
                     float* __restrict__ Qo, float* __restrict__ Ko, float* __restrict__ Vo)
{
    __shared__ float As[16][132];   // [k][m], padded row (132*4B % 16B == 0)
    __shared__ float Bs[16][132];   // [k][n]

    const int tid = threadIdx.x;
    const int ty = tid >> 4, tx = tid & 15;
    const int m0  = blockIdx.y * 128;
    const int nc0 = blockIdx.x * 128;
    const int wsel  = nc0 >> 10;          // which of Wq/Wk/Wv (1024 % 128 == 0)
    const int n_in0 = nc0 & 1023;

    const float* W  = (wsel == 0) ? Wq : (wsel == 1) ? Wk : Wv;
    const float* bi = (wsel == 0) ? bq : (wsel == 1) ? bk : bv;
    float* Out      = (wsel == 0) ? Qo : (wsel == 1) ? Ko : Vo;

    float acc[2][2][4][4];
#pragma unroll
    for (int a = 0; a < 2; ++a)
#pragma unroll
        for (int c = 0; c < 2; ++c)
#pragma unroll
            for (int i = 0; i < 4; ++i)
#pragma unroll
                for (int j = 0; j < 4; ++j) acc[a][c][i][j] = 0.f;

    const int lrow = tid >> 2;   // 0..63
    const int lkq  = tid & 3;    // 0..3  (k-quad)

    for (int k0 = 0; k0 < D_; k0 += 16) {
#pragma unroll
        for (int r = 0; r < 2; ++r) {
            const int row = lrow + r * 64;
            float4 av = *(const float4*)&X[(size_t)(m0 + row) * D_ + k0 + lkq * 4];
            float4 wv = *(const float4*)&W[(size_t)(n_in0 + row) * D_ + k0 + lkq * 4];
            As[lkq * 4 + 0][row] = av.x; As[lkq * 4 + 1][row] = av.y;
            As[lkq * 4 + 2][row] = av.z; As[lkq * 4 + 3][row] = av.w;
            Bs[lkq * 4 + 0][row] = wv.x; Bs[lkq * 4 + 1][row] = wv.y;
            Bs[lkq * 4 + 2][row] = wv.z; Bs[lkq * 4 + 3][row] = wv.w;
        }
        __syncthreads();

#pragma unroll
        for (int k = 0; k < 16; ++k) {
            float4 a0 = *(const float4*)&As[k][ty * 4];
            float4 a1 = *(const float4*)&As[k][64 + ty * 4];
            float4 b0 = *(const float4*)&Bs[k][tx * 4];
            float4 b1 = *(const float4*)&Bs[k][64 + tx * 4];
            float ar[2][4] = {{a0.x, a0.y, a0.z, a0.w}, {a1.x, a1.y, a1.z, a1.w}};
            float br[2][4] = {{b0.x, b0.y, b0.z, b0.w}, {b1.x, b1.y, b1.z, b1.w}};
#pragma unroll
            for (int ra = 0; ra < 2; ++ra)
#pragma unroll
                for (int rb = 0; rb < 2; ++rb)
#pragma unroll
                    for (int i = 0; i < 4; ++i)
#pragma unroll
                        for (int j = 0; j < 4; ++j)
                            acc[ra][rb][i][j] = fmaf(ar[ra][i], br[rb][j], acc[ra][rb][i][j]);
        }
        __syncthreads();
    }

    const int b = m0 >> 11;          // m0 / 2048 (128 | 2048, no straddle)
#pragma unroll
    for (int ra = 0; ra < 2; ++ra)
#pragma unroll
        for (int i = 0; i < 4; ++i) {
            const int m = m0 + ra * 64 + ty * 4 + i;
            const int s = m & (S_ - 1);
#pragma unroll
            for (int rb = 0; rb < 2; ++rb) {
                const int n_in = n_in0 + rb * 64 + tx * 4;
                const int h = n_in >> 6;
                const int d = n_in & 63;
                float4 v;
                v.x = acc[ra][rb][i][0] + bi[n_in + 0];
                v.y = acc[ra][rb][i][1] + bi[n_in + 1];
                v.z = acc[ra][rb][i][2] + bi[n_in + 2];
                v.w = acc[ra][rb][i][3] + bi[n_in + 3];
                *(float4*)&Out[(((size_t)b * H_ + h) * S_ + s) * HD_ + d] = v;
            }
        }
}

// ---------------------------------------------------------------------------
// In-place RoPE on Q (blockIdx.y==0) or K (==1), layout [B*H, S, 64].
// Lane d pairs with lane d^32 inside one 64-lane wave.
// ---------------------------------------------------------------------------
__global__ __launch_bounds__(256)
void rope_kernel(float* __restrict__ Q, float* __restrict__ K,
                 const float* __restrict__ cosT, const float* __restrict__ sinT)
{
    float* A = (blockIdx.y == 0) ? Q : K;
    const size_t e = (size_t)blockIdx.x * 256 + threadIdx.x;
    const int d    = (int)(e & 63);
    const int srow = (int)((e >> 6) & (S_ - 1));
    float x = A[e];
    float p = __shfl_xor(x, 32, 64);
    const int dm = d & 31;
    float c  = cosT[srow * 32 + dm];
    float sn = sinT[srow * 32 + dm];
    A[e] = (d < 32) ? fmaf(x, c, -p * sn) : fmaf(x, c, p * sn);
}

// ---------------------------------------------------------------------------
// Sliding-window attention, flash-style online softmax.
// Block: one (b,h), 64 query rows. 256 thr: thread (ty,tx) owns 4x4 of the
// 64x64 S-tile / O-tile. K-tile LDS is reused for P after a barrier.
// NOTE: reference MULTIPLIES scores by sqrt(64)=8.
// ---------------------------------------------------------------------------
__global__ __launch_bounds__(256)
void attn_kernel(const float* __restrict__ Q, const float* __restrict__ K,
                 const float* __restrict__ V, const int* __restrict__ amask,
                 float* __restrict__ out)
{
    __shared__ float Qs[64][68];
    __shared__ float KPs[64][68];   // K tile, then P tile
    __shared__ float Vs[64][68];

    const int tid = threadIdx.x;
    const int ty = tid >> 4, tx = tid & 15;
    const int bh = blockIdx.x;
    const int b  = bh >> 4;
    const int h  = bh & 15;
    const int i0 = blockIdx.y * 64;

    const float* Qb = Q + (size_t)bh * S_ * HD_;
    const float* Kb = K + (size_t)bh * S_ * HD_;
    const float* Vb = V + (size_t)bh * S_ * HD_;

#pragma unroll
    for (int r = 0; r < 4; ++r) {
        const int qi = tid + r * 256;
        const int row = qi >> 4, q4 = qi & 15;
        *(float4*)&Qs[row][q4 * 4] = *(const float4*)&Qb[(size_t)(i0 + row) * HD_ + q4 * 4];
    }

    float m_[4], l_[4], O_[4][4];
#pragma unroll
    for (int i = 0; i < 4; ++i) {
        m_[i] = -3.0e38f; l_[i] = 0.f;
#pragma unroll
        for (int j = 0; j < 4; ++j) O_[i][j] = 0.f;
    }

    const int jlo   = (i0 - WIN_ > 0) ? (i0 - WIN_) : 0;            // 64-aligned
    const int jhiex = (i0 + 64 + WIN_ < S_) ? (i0 + 64 + WIN_) : S_;

    for (int jt = jlo; jt < jhiex; jt += 64) {
        __syncthreads();   // previous PV done before overwriting KPs/Vs
#pragma unroll
        for (int r = 0; r < 4; ++r) {
            const int qi = tid + r * 256;
            const int row = qi >> 4, q4 = qi & 15;
            *(float4*)&KPs[row][q4 * 4] = *(const float4*)&Kb[(size_t)(jt + row) * HD_ + q4 * 4];
            *(float4*)&Vs[row][q4 * 4]  = *(const float4*)&Vb[(size_t)(jt + row) * HD_ + q4 * 4];
        }
        __syncthreads();

        // ---- S = Q @ K^T ----
        float sacc[4][4];
#pragma unroll
        for (int i = 0; i < 4; ++i)
#pragma unroll
            for (int j = 0; j < 4; ++j) sacc[i][j] = 0.f;

#pragma unroll
        for (int d4 = 0; d4 < 16; ++d4) {
            float qa[4][4], ka[4][4];
#pragma unroll
            for (int i = 0; i < 4; ++i)
                *(float4*)&qa[i][0] = *(const float4*)&Qs[ty * 4 + i][d4 * 4];
#pragma unroll
            for (int j = 0; j < 4; ++j)
                *(float4*)&ka[j][0] = *(const float4*)&KPs[tx * 4 + j][d4 * 4];
#pragma unroll
            for (int i = 0; i < 4; ++i)
#pragma unroll
                for (int j = 0; j < 4; ++j)
#pragma unroll
                    for (int e = 0; e < 4; ++e)
                        sacc[i][j] = fmaf(qa[i][e], ka[j][e], sacc[i][j]);
        }

        // ---- online softmax ----
        const int jj0 = jt + tx * 4;
        bool kmv[4];
#pragma unroll
        for (int j = 0; j < 4; ++j) kmv[j] = (amask[b * S_ + jj0 + j] > 0);

        float p_[4][4];
#pragma unroll
        for (int i = 0; i < 4; ++i) {
            const int qrow = i0 + ty * 4 + i;
            float sv[4];
            float rowm = -3.0e38f;
#pragma unroll
            for (int j = 0; j < 4; ++j) {
                const int jj = jj0 + j;
                const bool allow = kmv[j] && (jj >= qrow - WIN_) && (jj <= qrow + WIN_);
                sv[j] = allow ? (sacc[i][j] * 8.0f) : -3.0e38f;
                rowm = fmaxf(rowm, sv[j]);
            }
#pragma unroll
            for (int sh = 8; sh >= 1; sh >>= 1)
                rowm = fmaxf(rowm, __shfl_xor(rowm, sh, 64));
            const float mnew = fmaxf(m_[i], rowm);
            const float corr = __expf(m_[i] - mnew);   // 0 if m_ was -inf-ish, 1 if equal
            float rs = 0.f;
#pragma unroll
            for (int j = 0; j < 4; ++j) {
                const float pv = (sv[j] > -1.0e37f) ? __expf(sv[j] - mnew) : 0.f;
                p_[i][j] = pv;
                rs += pv;
            }
#pragma unroll
            for (int sh = 8; sh >= 1; sh >>= 1)
                rs += __shfl_xor(rs, sh, 64);
            l_[i] = l_[i] * corr + rs;
            m_[i] = mnew;
#pragma unroll
            for (int j = 0; j < 4; ++j) O_[i][j] *= corr;
        }

        __syncthreads();   // everyone done reading K from KPs
#pragma unroll
        for (int i = 0; i < 4; ++i)
            *(float4*)&KPs[ty * 4 + i][tx * 4] = *(const float4*)&p_[i][0];
        __syncthreads();

        // ---- O += P @ V ----
#pragma unroll
        for (int c4 = 0; c4 < 16; ++c4) {
            float pa[4][4], va[4][4];
#pragma unroll
            for (int i = 0; i < 4; ++i)
                *(float4*)&pa[i][0] = *(const float4*)&KPs[ty * 4 + i][c4 * 4];
#pragma unroll
            for (int c = 0; c < 4; ++c)
                *(float4*)&va[c][0] = *(const float4*)&Vs[c4 * 4 + c][tx * 4];
#pragma unroll
            for (int i = 0; i < 4; ++i)
#pragma unroll
                for (int c = 0; c < 4; ++c)
#pragma unroll
                    for (int j = 0; j < 4; ++j)
                        O_[i][j] = fmaf(pa[i][c], va[c][j], O_[i][j]);
        }
    }

    // ---- epilogue: normalize, query-mask, write [B,S,D] ----
#pragma unroll
    for (int i = 0; i < 4; ++i) {
        const int qrow = i0 + ty * 4 + i;
        const float rl = (l_[i] > 0.f) ? (1.0f / l_[i]) : 0.f;
        const float qm = (amask[b * S_ + qrow] > 0) ? 1.f : 0.f;
        const float f = rl * qm;
        float4 v;
        v.x = O_[i][0] * f; v.y = O_[i][1] * f;
        v.z = O_[i][2] * f; v.w = O_[i][3] * f;
        *(float4*)&out[((size_t)b * S_ + qrow) * D_ + h * HD_ + tx * 4] = v;
    }
}

// ---------------------------------------------------------------------------
extern "C" void kernel_launch(void* const* d_in, const int* in_sizes, int n_in,
                              void* d_out, int out_size, void* d_ws, size_t ws_size,
                              hipStream_t stream)
{
    const float* X  = (const float*)d_in[0];
    const int*   am = (const int*)d_in[1];
    const float* Wq = (const float*)d_in[2];
    const float* bq = (const float*)d_in[3];
    const float* Wk = (const float*)d_in[4];
    const float* bk = (const float*)d_in[5];
    const float* Wv = (const float*)d_in[6];
    const float* bv = (const float*)d_in[7];
    float* out = (float*)d_out;

    float* ws = (float*)d_ws;
    const size_t nqkv = (size_t)B_ * H_ * S_ * HD_;   // 4,194,304
    float* Qw   = ws;
    float* Kw   = Qw + nqkv;
    float* Vw   = Kw + nqkv;
    float* cosT = Vw + nqkv;
    float* sinT = cosT + (size_t)S_ * 32;

    rope_table_kernel<<<dim3((S_ * 32 + 255) / 256), dim3(256), 0, stream>>>(cosT, sinT);
    qkv_gemm_kernel<<<dim3(24, 32), dim3(256), 0, stream>>>(X, Wq, Wk, Wv, bq, bk, bv,
                                                            Qw, Kw, Vw);
    rope_kernel<<<dim3((unsigned)(nqkv / 256), 2), dim3(256), 0, stream>>>(Qw, Kw, cosT, sinT);
    attn_kernel<<<dim3(B_ * H_, S_ / 64), dim3(256), 0, stream>>>(Qw, Kw, Vw, am, out);
}